// Round 1
// baseline (7201.234 us; speedup 1.0000x reference)
//
#include <hip/hip_runtime.h>
#include <math.h>

#define NNODES 100000
#define NEDGES 200000
#define HD 64
#define NP2 250000
#define NP3 500000
#define NG 2048
#define NCLS 10
#define NFEAT 18
#define EFEAT 18

__device__ __forceinline__ float sigf(float x) { return 1.0f / (1.0f + expf(-x)); }

// ---------------------------------------------------------------------------
// Weight prep: Bt[k][j] (192x256), k<128 from w_ih[j][k], k>=128 from w_hh[j][k-128]
// bsum[j] = b_ih[j] + b_hh[j]
// ---------------------------------------------------------------------------
__global__ void prep_weights(const float* __restrict__ w_ih, const float* __restrict__ w_hh,
                             const float* __restrict__ b_ih, const float* __restrict__ b_hh,
                             float* __restrict__ Bt, float* __restrict__ bsum) {
    int gid = blockIdx.x * 256 + threadIdx.x;
    if (gid < 192 * 256) {
        int k = gid >> 8, j = gid & 255;
        Bt[k * 256 + j] = (k < 128) ? w_ih[j * 128 + k] : w_hh[j * 64 + (k - 128)];
    } else if (gid < 192 * 256 + 256) {
        int j = gid - 192 * 256;
        bsum[j] = b_ih[j] + b_hh[j];
    }
}

// ---------------------------------------------------------------------------
// Feature encoder: out[n][j] = sum_k X[n][k]*Wf[k][j] + bf[j]
// ---------------------------------------------------------------------------
__global__ void encode(const float* __restrict__ X, const float* __restrict__ Wf,
                       const float* __restrict__ bf, float* __restrict__ out,
                       long n, int F) {
    long gid = (long)blockIdx.x * 256 + threadIdx.x;
    if (gid >= n * 64) return;
    long r = gid >> 6;
    int col = (int)(gid & 63);
    float acc = bf[col];
    const float* xr = X + r * F;
    for (int k = 0; k < F; ++k) acc += xr[k] * Wf[k * 64 + col];
    out[gid] = acc;
}

// ---------------------------------------------------------------------------
// LSTM path conv.  Block = 256 threads handles 32 paths through all L steps.
// A (LDS): [k][p] k<128 = xt (node feat | edge enc), k in 128..191 = h state.
// Bg (LDS): union of streamed B chunk (32x256, stride 260) and gates (32 paths x 256).
// c state in registers (thread owns fixed (path, 8 hidden) slice).
// Final-step h is atomically scattered into hsum[last_node].
// ---------------------------------------------------------------------------
#define MAC4(Q, M0)                                                     \
    acc0[M0 + 0] += av.x * Q.x; acc0[M0 + 1] += av.x * Q.y;             \
    acc0[M0 + 2] += av.x * Q.z; acc0[M0 + 3] += av.x * Q.w;             \
    acc1[M0 + 0] += av.y * Q.x; acc1[M0 + 1] += av.y * Q.y;             \
    acc1[M0 + 2] += av.y * Q.z; acc1[M0 + 3] += av.y * Q.w;

#define SET4(Q, M0)                                                     \
    acc0[M0] = Q.x; acc0[M0 + 1] = Q.y; acc0[M0 + 2] = Q.z; acc0[M0 + 3] = Q.w; \
    acc1[M0] = Q.x; acc1[M0 + 1] = Q.y; acc1[M0 + 2] = Q.z; acc1[M0 + 3] = Q.w;

template <int L>
__global__ __launch_bounds__(256, 2)
void conv_lstm(const float* __restrict__ x_in, const float* __restrict__ ea_enc,
               const int* __restrict__ paths, const int* __restrict__ ei,
               const float* __restrict__ Bt, const float* __restrict__ bsum,
               float* __restrict__ hsum, int P) {
    __shared__ float A[192 * 36];   // [k][p], stride 36
    __shared__ float Bg[32 * 260];  // B chunk / gates, stride 260

    const int t = threadIdx.x;
    const int tx = t & 15, ty = t >> 4;        // GEMM tile: j-chunk / path-pair
    const int pl = t >> 3, kq = (t & 7) * 8;   // gather + activation mapping
    const int pg = blockIdx.x * 32 + pl;
    const int pc = pg < P ? pg : P - 1;

    // zero h rows (k = 128..191)
    for (int i = t; i < 64 * 36; i += 256) A[128 * 36 + i] = 0.f;

    float creg[8];
#pragma unroll
    for (int i = 0; i < 8; ++i) creg[i] = 0.f;

    float acc0[16], acc1[16];

    for (int step = 0; step < L; ++step) {
        // ---- gather xt into A rows 0..127 (x part 0..63, edge part 64..127)
        {
            int node = paths[pc * L + step];
            const float* xr = x_in + (size_t)node * HD + kq;
            float4 v0 = *(const float4*)xr;
            float4 v1 = *(const float4*)(xr + 4);
            A[(kq + 0) * 36 + pl] = v0.x;
            A[(kq + 1) * 36 + pl] = v0.y;
            A[(kq + 2) * 36 + pl] = v0.z;
            A[(kq + 3) * 36 + pl] = v0.w;
            A[(kq + 4) * 36 + pl] = v1.x;
            A[(kq + 5) * 36 + pl] = v1.y;
            A[(kq + 6) * 36 + pl] = v1.z;
            A[(kq + 7) * 36 + pl] = v1.w;
            if (step == 0) {
#pragma unroll
                for (int i = 0; i < 8; ++i) A[(64 + kq + i) * 36 + pl] = 0.f;
            } else {
                int e = ei[pc * (L - 1) + (step - 1)];
                const float* er = ea_enc + (size_t)e * HD + kq;
                float4 w0 = *(const float4*)er;
                float4 w1 = *(const float4*)(er + 4);
                A[(64 + kq + 0) * 36 + pl] = w0.x;
                A[(64 + kq + 1) * 36 + pl] = w0.y;
                A[(64 + kq + 2) * 36 + pl] = w0.z;
                A[(64 + kq + 3) * 36 + pl] = w0.w;
                A[(64 + kq + 4) * 36 + pl] = w1.x;
                A[(64 + kq + 5) * 36 + pl] = w1.y;
                A[(64 + kq + 6) * 36 + pl] = w1.z;
                A[(64 + kq + 7) * 36 + pl] = w1.w;
            }
        }
        // ---- init accumulators with bias
        {
            const float4* b4 = (const float4*)(bsum + tx * 16);
            float4 q0 = b4[0], q1 = b4[1], q2 = b4[2], q3 = b4[3];
            SET4(q0, 0) SET4(q1, 4) SET4(q2, 8) SET4(q3, 12)
        }
        // ---- GEMM: gates[32 x 256] = A^T (32x192) * B (192x256)
        for (int kb = 0; kb < 192; kb += 32) {
            __syncthreads();  // A/gather writes visible; previous Bg readers done
            {
                int j4 = (t & 63) * 4;
                int kr0 = t >> 6;
#pragma unroll
                for (int kk = 0; kk < 8; ++kk) {
                    int kr = kr0 + kk * 4;
                    *(float4*)(Bg + kr * 260 + j4) =
                        *(const float4*)(Bt + (size_t)(kb + kr) * 256 + j4);
                }
            }
            __syncthreads();
#pragma unroll 8
            for (int kk = 0; kk < 32; ++kk) {
                float2 av = *(const float2*)(A + (kb + kk) * 36 + 2 * ty);
                const float4* bg4 = (const float4*)(Bg + kk * 260 + tx * 16);
                float4 q0 = bg4[0], q1 = bg4[1], q2 = bg4[2], q3 = bg4[3];
                MAC4(q0, 0) MAC4(q1, 4) MAC4(q2, 8) MAC4(q3, 12)
            }
        }
        __syncthreads();  // all Bg/A reads done -> reuse Bg for gates
        // ---- write gates to LDS
        {
            float* g0 = Bg + (2 * ty) * 260 + tx * 16;
            float* g1 = Bg + (2 * ty + 1) * 260 + tx * 16;
            *(float4*)(g0 + 0)  = make_float4(acc0[0], acc0[1], acc0[2], acc0[3]);
            *(float4*)(g0 + 4)  = make_float4(acc0[4], acc0[5], acc0[6], acc0[7]);
            *(float4*)(g0 + 8)  = make_float4(acc0[8], acc0[9], acc0[10], acc0[11]);
            *(float4*)(g0 + 12) = make_float4(acc0[12], acc0[13], acc0[14], acc0[15]);
            *(float4*)(g1 + 0)  = make_float4(acc1[0], acc1[1], acc1[2], acc1[3]);
            *(float4*)(g1 + 4)  = make_float4(acc1[4], acc1[5], acc1[6], acc1[7]);
            *(float4*)(g1 + 8)  = make_float4(acc1[8], acc1[9], acc1[10], acc1[11]);
            *(float4*)(g1 + 12) = make_float4(acc1[12], acc1[13], acc1[14], acc1[15]);
        }
        __syncthreads();
        // ---- activation: i,f,g,o -> c,h  (thread owns (pl, hh=kq..kq+7))
        {
            const int hb = kq;
#pragma unroll
            for (int i = 0; i < 8; ++i) {
                int hh = hb + i;
                float gi = Bg[pl * 260 + hh];
                float gf = Bg[pl * 260 + 64 + hh];
                float gg = Bg[pl * 260 + 128 + hh];
                float go = Bg[pl * 260 + 192 + hh];
                float cn = sigf(gf) * creg[i] + sigf(gi) * tanhf(gg);
                float hn = sigf(go) * tanhf(cn);
                creg[i] = cn;
                if (step < L - 1) {
                    A[(128 + hh) * 36 + pl] = hn;
                } else if (pg < P) {
                    int nodeL = paths[pg * L + (L - 1)];
                    atomicAdd(hsum + (size_t)nodeL * HD + hh, hn);
                }
            }
        }
        // next iteration's first __syncthreads in kb-loop fences activation
    }
}

// ---------------------------------------------------------------------------
// Per-column sum / sumsq over rows (for BN stats)
// ---------------------------------------------------------------------------
__global__ void col_stats(const float* __restrict__ X, int nrows, float* __restrict__ out) {
    int col = threadIdx.x & 63, rg = threadIdx.x >> 6;
    float s = 0.f, q = 0.f;
    long stride = (long)gridDim.x * 4;
    for (long r = (long)blockIdx.x * 4 + rg; r < nrows; r += stride) {
        float v = X[r * 64 + col];
        s += v;
        q += v * v;
    }
    __shared__ float red[2][256];
    red[0][threadIdx.x] = s;
    red[1][threadIdx.x] = q;
    __syncthreads();
    if (threadIdx.x < 64) {
        int c = threadIdx.x;
        float ss = red[0][c] + red[0][c + 64] + red[0][c + 128] + red[0][c + 192];
        float qq = red[1][c] + red[1][c + 64] + red[1][c + 128] + red[1][c + 192];
        atomicAdd(out + c, ss);
        atomicAdd(out + 64 + c, qq);
    }
}

// stats -> per-column affine: y = x*a + c  implements BN(g,b)
__global__ void bn_finalize(const float* __restrict__ stats, const float* __restrict__ g,
                            const float* __restrict__ b, int nrows, float* __restrict__ ab) {
    int h = threadIdx.x;
    if (h >= 64) return;
    float inv = 1.0f / (float)nrows;
    float mean = stats[h] * inv;
    float var = stats[64 + h] * inv - mean * mean;
    float a = g[h] * rsqrtf(var + 1e-5f);
    ab[h] = a;
    ab[64 + h] = b[h] - mean * a;
}

// ---------------------------------------------------------------------------
// Y[n][j] = sum_k inAct(X[n][k]*a[k]+c[k]) * W[k][j] + bias[j]
// optional fused column stats of Y (pre-activation values of the NEXT BN)
// ---------------------------------------------------------------------------
template <bool INRELU, bool STATS>
__global__ __launch_bounds__(256)
void gemm64(const float* __restrict__ X, const float* __restrict__ ab,
            const float* __restrict__ W, const float* __restrict__ bias,
            float* __restrict__ Y, float* stats, int nrows) {
    __shared__ float Xs[64 * 64];
    __shared__ float red[2][256];
    const int t = threadIdx.x;
    const int col = t & 63, rg = t >> 6;
    const long r0 = (long)blockIdx.x * 64;

    float a = 1.f, c = 0.f;
    if (ab) { a = ab[col]; c = ab[64 + col]; }

    for (int i = 0; i < 16; ++i) {
        int rl = rg * 16 + i;
        long r = r0 + rl;
        float v = (r < nrows) ? X[r * 64 + col] : 0.f;
        v = v * a + c;
        if (INRELU) v = fmaxf(v, 0.f);
        Xs[rl * 64 + col] = v;
    }
    __syncthreads();

    float wreg[64];
#pragma unroll
    for (int k = 0; k < 64; ++k) wreg[k] = W[k * 64 + col];
    float bs = bias[col];
    float ssum = 0.f, ssq = 0.f;

    for (int i = 0; i < 16; ++i) {
        int rl = rg * 16 + i;
        long r = r0 + rl;
        const float4* xs4 = (const float4*)(Xs + rl * 64);
        float acc = bs;
#pragma unroll
        for (int k4 = 0; k4 < 16; ++k4) {
            float4 xv = xs4[k4];
            acc += xv.x * wreg[4 * k4] + xv.y * wreg[4 * k4 + 1] +
                   xv.z * wreg[4 * k4 + 2] + xv.w * wreg[4 * k4 + 3];
        }
        if (r < nrows) {
            Y[r * 64 + col] = acc;
            ssum += acc;
            ssq += acc * acc;
        }
    }
    if (STATS) {
        red[0][t] = ssum;
        red[1][t] = ssq;
        __syncthreads();
        if (t < 64) {
            float s = red[0][t] + red[0][t + 64] + red[0][t + 128] + red[0][t + 192];
            float q = red[1][t] + red[1][t + 64] + red[1][t + 128] + red[1][t + 192];
            atomicAdd(stats + t, s);
            atomicAdd(stats + 64 + t, q);
        }
    }
}

// Wio = relu(Wio*a + c); optionally Win = 0.75*W0 - 0.25*Wio
__global__ void bn_apply(float* __restrict__ Wio, const float* __restrict__ ab,
                         const float* __restrict__ W0, float* __restrict__ Win, long n) {
    long gid = (long)blockIdx.x * 256 + threadIdx.x;
    if (gid >= n * 64) return;
    int col = (int)(gid & 63);
    float v = fmaxf(Wio[gid] * ab[col] + ab[64 + col], 0.f);
    Wio[gid] = v;
    if (Win) Win[gid] = 0.75f * W0[gid] - 0.25f * v;
}

// per-column dots: atts[h] += sum_n W0*W1 ; atts[64+h] += sum_n W0*W2
__global__ void att_scores(const float* __restrict__ W0, const float* __restrict__ W1,
                           const float* __restrict__ W2, float* __restrict__ atts, int n) {
    int col = threadIdx.x & 63, rg = threadIdx.x >> 6;
    float s1 = 0.f, s2 = 0.f;
    long stride = (long)gridDim.x * 4;
    for (long r = (long)blockIdx.x * 4 + rg; r < n; r += stride) {
        float q = W0[r * 64 + col];
        s1 += q * W1[r * 64 + col];
        s2 += q * W2[r * 64 + col];
    }
    __shared__ float red[2][256];
    red[0][threadIdx.x] = s1;
    red[1][threadIdx.x] = s2;
    __syncthreads();
    if (threadIdx.x < 64) {
        int c = threadIdx.x;
        float a1 = red[0][c] + red[0][c + 64] + red[0][c + 128] + red[0][c + 192];
        float a2 = red[1][c] + red[1][c + 64] + red[1][c + 128] + red[1][c + 192];
        atomicAdd(atts + c, a1);
        atomicAdd(atts + 64 + c, a2);
    }
}

// single wave: normalize scores, dot w_att, softmax over the 2 -> watt[0..1]
__global__ void att_softmax(const float* __restrict__ atts, const float* __restrict__ w_att,
                            const float* __restrict__ b_att, float* __restrict__ watt) {
    int h = threadIdx.x;  // 0..63
    float z[2];
    for (int k = 0; k < 2; ++k) {
        float s = atts[64 * k + h];
        float mn = s, mx = s;
        for (int off = 32; off > 0; off >>= 1) {
            mn = fminf(mn, __shfl_down(mn, off));
            mx = fmaxf(mx, __shfl_down(mx, off));
        }
        mn = __shfl(mn, 0);
        mx = __shfl(mx, 0);
        float sn = (s - mn) / (mx - mn + 1e-6f);
        float d = sn * w_att[h];
        for (int off = 32; off > 0; off >>= 1) d += __shfl_down(d, off);
        z[k] = __shfl(d, 0) + b_att[0];
    }
    if (h == 0) {
        float m = fmaxf(z[0], z[1]);
        float e0 = expf(z[0] - m), e1 = expf(z[1] - m);
        float inv = 1.0f / (e0 + e1);
        watt[0] = e0 * inv;
        watt[1] = e1 * inv;
    }
}

// rep = W0 + w1*W1 + w2*W2, scatter-add into pooled[batch[n]]
__global__ void pool_rep(const float* __restrict__ W0, const float* __restrict__ W1,
                         const float* __restrict__ W2, const float* __restrict__ watt,
                         const int* __restrict__ batch, float* __restrict__ pooled, int n) {
    long gid = (long)blockIdx.x * 256 + threadIdx.x;
    if (gid >= (long)n * 64) return;
    long r = gid >> 6;
    int col = (int)(gid & 63);
    float w1 = watt[0], w2 = watt[1];
    float rep = W0[gid] + w1 * W1[gid] + w2 * W2[gid];
    atomicAdd(pooled + (size_t)batch[r] * 64 + col, rep);
}

// out[g][j] = sum_k relu(X[g][k]) * W[k][j] + b[j]   (W is 64 x 10)
__global__ void lin2_kernel(const float* __restrict__ X, const float* __restrict__ W,
                            const float* __restrict__ b, float* __restrict__ out, int g_count) {
    int gid = blockIdx.x * 256 + threadIdx.x;
    if (gid >= g_count * NCLS) return;
    int g = gid / NCLS, j = gid - g * NCLS;
    float acc = b[j];
    const float* xr = X + (size_t)g * 64;
    for (int k = 0; k < 64; ++k) acc += fmaxf(xr[k], 0.f) * W[k * NCLS + j];
    out[gid] = acc;
}

// ---------------------------------------------------------------------------
extern "C" void kernel_launch(void* const* d_in, const int* in_sizes, int n_in,
                              void* d_out, int out_size, void* d_ws, size_t ws_size,
                              hipStream_t stream) {
    const float* x         = (const float*)d_in[0];
    const float* edge_attr = (const float*)d_in[1];
    const int*   paths2    = (const int*)d_in[2];
    const int*   ei2       = (const int*)d_in[3];
    const int*   paths3    = (const int*)d_in[4];
    const int*   ei3       = (const int*)d_in[5];
    const int*   batch     = (const int*)d_in[6];
    const float* w_feat    = (const float*)d_in[7];
    const float* b_feat    = (const float*)d_in[8];
    const float* w_bond    = (const float*)d_in[9];
    const float* b_bond    = (const float*)d_in[10];
    const float* w_ih      = (const float*)d_in[11];
    const float* w_hh      = (const float*)d_in[12];
    const float* b_ih      = (const float*)d_in[13];
    const float* b_hh      = (const float*)d_in[14];
    const float* bn_g      = (const float*)d_in[15];
    const float* bn_b      = (const float*)d_in[16];
    const float* mlp_w1    = (const float*)d_in[17];
    const float* mlp_b1    = (const float*)d_in[18];
    const float* bn1_g     = (const float*)d_in[19];
    const float* bn1_b     = (const float*)d_in[20];
    const float* mlp_w2    = (const float*)d_in[21];
    const float* mlp_b2    = (const float*)d_in[22];
    const float* bn2_g     = (const float*)d_in[23];
    const float* bn2_b     = (const float*)d_in[24];
    const float* w_att     = (const float*)d_in[25];
    const float* b_att     = (const float*)d_in[26];
    const float* w_l1      = (const float*)d_in[27];
    const float* b_l1      = (const float*)d_in[28];
    const float* w_l2      = (const float*)d_in[29];
    const float* b_l2      = (const float*)d_in[30];

    float* ws = (float*)d_ws;
    float* W0     = ws;                               // N*64
    float* ea     = W0 + (size_t)NNODES * 64;         // E*64
    float* Win    = ea + (size_t)NEDGES * 64;         // N*64
    float* W1     = Win + (size_t)NNODES * 64;        // N*64
    float* W2     = W1 + (size_t)NNODES * 64;         // N*64
    float* Wtmp   = W2 + (size_t)NNODES * 64;         // N*64
    float* hsum   = Wtmp + (size_t)NNODES * 64;       // N*64
    float* Bt     = hsum + (size_t)NNODES * 64;       // 192*256
    float* bsum   = Bt + 192 * 256;                   // 256
    float* st     = bsum + 256;                       // 6*128
    float* abuf   = st + 6 * 128;                     // 6*128
    float* atts   = abuf + 6 * 128;                   // 128
    float* watt   = atts + 128;                       // 64 (2 used)
    float* pooled = watt + 64;                        // G*64
    float* lin1   = pooled + (size_t)NG * 64;         // G*64

    // zero: stats region (st..watt inclusive), pooled, hsum
    hipMemsetAsync(st, 0, (6 * 128 + 6 * 128 + 128 + 64) * sizeof(float), stream);
    hipMemsetAsync(pooled, 0, (size_t)NG * 64 * sizeof(float), stream);
    hipMemsetAsync(hsum, 0, (size_t)NNODES * 64 * sizeof(float), stream);

    prep_weights<<<193, 256, 0, stream>>>(w_ih, w_hh, b_ih, b_hh, Bt, bsum);
    encode<<<(NNODES * 64 + 255) / 256, 256, 0, stream>>>(x, w_feat, b_feat, W0, NNODES, NFEAT);
    encode<<<(NEDGES * 64 + 255) / 256, 256, 0, stream>>>(edge_attr, w_bond, b_bond, ea, NEDGES, EFEAT);

    // ---------------- conv 1 (L=2) ----------------
    conv_lstm<2><<<(NP2 + 31) / 32, 256, 0, stream>>>(W0, ea, paths2, ei2, Bt, bsum, hsum, NP2);

    col_stats<<<256, 256, 0, stream>>>(hsum, NNODES, st + 0);
    bn_finalize<<<1, 64, 0, stream>>>(st + 0, bn_g + 0, bn_b + 0, NNODES, abuf + 0);
    gemm64<false, true><<<(NNODES + 63) / 64, 256, 0, stream>>>(hsum, abuf + 0, mlp_w1, mlp_b1, Wtmp, st + 128, NNODES);
    bn_finalize<<<1, 64, 0, stream>>>(st + 128, bn1_g + 0, bn1_b + 0, NNODES, abuf + 128);
    gemm64<true, true><<<(NNODES + 63) / 64, 256, 0, stream>>>(Wtmp, abuf + 128, mlp_w2, mlp_b2, W1, st + 256, NNODES);
    bn_finalize<<<1, 64, 0, stream>>>(st + 256, bn2_g + 0, bn2_b + 0, NNODES, abuf + 256);
    bn_apply<<<(NNODES * 64 + 255) / 256, 256, 0, stream>>>(W1, abuf + 256, W0, Win, NNODES);

    // ---------------- conv 2 (L=3) ----------------
    hipMemsetAsync(hsum, 0, (size_t)NNODES * 64 * sizeof(float), stream);
    conv_lstm<3><<<(NP3 + 31) / 32, 256, 0, stream>>>(Win, ea, paths3, ei3, Bt, bsum, hsum, NP3);

    col_stats<<<256, 256, 0, stream>>>(hsum, NNODES, st + 384);
    bn_finalize<<<1, 64, 0, stream>>>(st + 384, bn_g + 64, bn_b + 64, NNODES, abuf + 384);
    gemm64<false, true><<<(NNODES + 63) / 64, 256, 0, stream>>>(hsum, abuf + 384, mlp_w1 + 4096, mlp_b1 + 64, Wtmp, st + 512, NNODES);
    bn_finalize<<<1, 64, 0, stream>>>(st + 512, bn1_g + 64, bn1_b + 64, NNODES, abuf + 512);
    gemm64<true, true><<<(NNODES + 63) / 64, 256, 0, stream>>>(Wtmp, abuf + 512, mlp_w2 + 4096, mlp_b2 + 64, W2, st + 640, NNODES);
    bn_finalize<<<1, 64, 0, stream>>>(st + 640, bn2_g + 64, bn2_b + 64, NNODES, abuf + 640);
    bn_apply<<<(NNODES * 64 + 255) / 256, 256, 0, stream>>>(W2, abuf + 640, nullptr, nullptr, NNODES);

    // ---------------- attention + pooling + head ----------------
    att_scores<<<256, 256, 0, stream>>>(W0, W1, W2, atts, NNODES);
    att_softmax<<<1, 64, 0, stream>>>(atts, w_att, b_att, watt);
    pool_rep<<<(NNODES * 64 + 255) / 256, 256, 0, stream>>>(W0, W1, W2, watt, batch, pooled, NNODES);
    gemm64<false, false><<<NG / 64, 256, 0, stream>>>(pooled, nullptr, w_l1, b_l1, lin1, nullptr, NG);
    lin2_kernel<<<(NG * NCLS + 255) / 256, 256, 0, stream>>>(lin1, w_l2, b_l2, (float*)d_out, NG);
}

// Round 2
// 5213.066 us; speedup vs baseline: 1.3814x; 1.3814x over previous
//
#include <hip/hip_runtime.h>
#include <math.h>

#define NNODES 100000
#define NEDGES 200000
#define HD 64
#define NP2 250000
#define NP3 500000
#define NG 2048
#define NCLS 10
#define NFEAT 18
#define EFEAT 18

__device__ __forceinline__ float sigf(float x) { return 1.0f / (1.0f + expf(-x)); }

// ---------------------------------------------------------------------------
// Weight prep: Bt[k][j] (192x256), k<128 from w_ih[j][k], k>=128 from w_hh[j][k-128]
// bsum[j] = b_ih[j] + b_hh[j]
// ---------------------------------------------------------------------------
__global__ void prep_weights(const float* __restrict__ w_ih, const float* __restrict__ w_hh,
                             const float* __restrict__ b_ih, const float* __restrict__ b_hh,
                             float* __restrict__ Bt, float* __restrict__ bsum) {
    int gid = blockIdx.x * 256 + threadIdx.x;
    if (gid < 192 * 256) {
        int k = gid >> 8, j = gid & 255;
        Bt[k * 256 + j] = (k < 128) ? w_ih[j * 128 + k] : w_hh[j * 64 + (k - 128)];
    } else if (gid < 192 * 256 + 256) {
        int j = gid - 192 * 256;
        bsum[j] = b_ih[j] + b_hh[j];
    }
}

// ---------------------------------------------------------------------------
// Feature encoder: out[n][j] = sum_k X[n][k]*Wf[k][j] + bf[j]
// ---------------------------------------------------------------------------
__global__ void encode(const float* __restrict__ X, const float* __restrict__ Wf,
                       const float* __restrict__ bf, float* __restrict__ out,
                       long n, int F) {
    long gid = (long)blockIdx.x * 256 + threadIdx.x;
    if (gid >= n * 64) return;
    long r = gid >> 6;
    int col = (int)(gid & 63);
    float acc = bf[col];
    const float* xr = X + r * F;
    for (int k = 0; k < F; ++k) acc += xr[k] * Wf[k * 64 + col];
    out[gid] = acc;
}

// ---------------------------------------------------------------------------
// LSTM path conv.  Block = 256 threads handles 32 paths through all L steps.
// A (LDS): [k][p] stride 34; k<128 = xt (node feat | edge enc), k 128..191 = h.
// Bg (LDS): streamed B chunk (32 x 256).
// Thread (tx,ty) owns paths {2ty, 2ty+1} x hidden {tx*4..tx*4+3}, with output
// columns {q*64 + tx*4 + i} = gate q for hidden tx*4+i  ->  activation fully
// in registers (c state too); h written back to A rows 128..191; final-step h
// atomically scattered to hsum[last_node].
// Bank conflicts: inner-loop B reads are 64-consecutive-float per quad
// (2-way broadcast = free); A reads broadcast; stride 34 keeps gather writes
// at <=4-way on 8 instr/step.
// ---------------------------------------------------------------------------
#define MAC4(Q, M0)                                                     \
    acc0[M0 + 0] += av.x * Q.x; acc0[M0 + 1] += av.x * Q.y;             \
    acc0[M0 + 2] += av.x * Q.z; acc0[M0 + 3] += av.x * Q.w;             \
    acc1[M0 + 0] += av.y * Q.x; acc1[M0 + 1] += av.y * Q.y;             \
    acc1[M0 + 2] += av.y * Q.z; acc1[M0 + 3] += av.y * Q.w;

#define SET4(Q, M0)                                                     \
    acc0[M0] = Q.x; acc0[M0 + 1] = Q.y; acc0[M0 + 2] = Q.z; acc0[M0 + 3] = Q.w; \
    acc1[M0] = Q.x; acc1[M0 + 1] = Q.y; acc1[M0 + 2] = Q.z; acc1[M0 + 3] = Q.w;

#define ASTRIDE 34

template <int L>
__global__ __launch_bounds__(256, 2)
void conv_lstm(const float* __restrict__ x_in, const float* __restrict__ ea_enc,
               const int* __restrict__ paths, const int* __restrict__ ei,
               const float* __restrict__ Bt, const float* __restrict__ bsum,
               float* __restrict__ hsum, int P) {
    __shared__ float A[192 * ASTRIDE];
    __shared__ float Bg[32 * 256];

    const int t = threadIdx.x;
    const int tx = t & 15, ty = t >> 4;        // tx: hidden quad, ty: path pair
    const int pl = t >> 3, kq = (t & 7) * 8;   // gather mapping
    const int pg = blockIdx.x * 32 + pl;
    const int pc = pg < P ? pg : P - 1;
    const int pga0 = blockIdx.x * 32 + 2 * ty;     // activation-owned paths
    const int pga1 = pga0 + 1;

    // zero h rows (k = 128..191)
    for (int i = t; i < 64 * ASTRIDE; i += 256) A[128 * ASTRIDE + i] = 0.f;

    float creg[8];
#pragma unroll
    for (int i = 0; i < 8; ++i) creg[i] = 0.f;

    // bias (gate-quad layout), loaded once
    float4 bias0 = *(const float4*)(bsum + 0 * 64 + tx * 4);
    float4 bias1 = *(const float4*)(bsum + 1 * 64 + tx * 4);
    float4 bias2 = *(const float4*)(bsum + 2 * 64 + tx * 4);
    float4 bias3 = *(const float4*)(bsum + 3 * 64 + tx * 4);

    float acc0[16], acc1[16];

    for (int step = 0; step < L; ++step) {
        // ---- gather xt into A rows 0..127 (x part 0..63, edge part 64..127)
        {
            int node = paths[pc * L + step];
            const float* xr = x_in + (size_t)node * HD + kq;
            float4 v0 = *(const float4*)xr;
            float4 v1 = *(const float4*)(xr + 4);
            A[(kq + 0) * ASTRIDE + pl] = v0.x;
            A[(kq + 1) * ASTRIDE + pl] = v0.y;
            A[(kq + 2) * ASTRIDE + pl] = v0.z;
            A[(kq + 3) * ASTRIDE + pl] = v0.w;
            A[(kq + 4) * ASTRIDE + pl] = v1.x;
            A[(kq + 5) * ASTRIDE + pl] = v1.y;
            A[(kq + 6) * ASTRIDE + pl] = v1.z;
            A[(kq + 7) * ASTRIDE + pl] = v1.w;
            if (step == 0) {
#pragma unroll
                for (int i = 0; i < 8; ++i) A[(64 + kq + i) * ASTRIDE + pl] = 0.f;
            } else {
                int e = ei[pc * (L - 1) + (step - 1)];
                const float* er = ea_enc + (size_t)e * HD + kq;
                float4 w0 = *(const float4*)er;
                float4 w1 = *(const float4*)(er + 4);
                A[(64 + kq + 0) * ASTRIDE + pl] = w0.x;
                A[(64 + kq + 1) * ASTRIDE + pl] = w0.y;
                A[(64 + kq + 2) * ASTRIDE + pl] = w0.z;
                A[(64 + kq + 3) * ASTRIDE + pl] = w0.w;
                A[(64 + kq + 4) * ASTRIDE + pl] = w1.x;
                A[(64 + kq + 5) * ASTRIDE + pl] = w1.y;
                A[(64 + kq + 6) * ASTRIDE + pl] = w1.z;
                A[(64 + kq + 7) * ASTRIDE + pl] = w1.w;
            }
        }
        // ---- init accumulators with bias
        SET4(bias0, 0) SET4(bias1, 4) SET4(bias2, 8) SET4(bias3, 12)

        // ---- GEMM: gates[32 x 256] = A^T (32x192) * B (192x256)
        for (int kb = 0; kb < 192; kb += 32) {
            __syncthreads();  // gather/h writes visible; previous Bg readers done
            {
                int j4 = (t & 63) * 4;
                int kr0 = t >> 6;
#pragma unroll
                for (int kk = 0; kk < 8; ++kk) {
                    int kr = kr0 + kk * 4;
                    *(float4*)(Bg + kr * 256 + j4) =
                        *(const float4*)(Bt + (size_t)(kb + kr) * 256 + j4);
                }
            }
            __syncthreads();
#pragma unroll 8
            for (int kk = 0; kk < 32; ++kk) {
                float2 av = *(const float2*)(A + (kb + kk) * ASTRIDE + 2 * ty);
                const float* br = Bg + kk * 256 + tx * 4;
                float4 q0 = *(const float4*)(br + 0);
                float4 q1 = *(const float4*)(br + 64);
                float4 q2 = *(const float4*)(br + 128);
                float4 q3 = *(const float4*)(br + 192);
                MAC4(q0, 0) MAC4(q1, 4) MAC4(q2, 8) MAC4(q3, 12)
            }
        }
        __syncthreads();  // GEMM A/Bg reads done before activation writes A

        // ---- activation in registers: acc[q*4+i] = gate q (i,f,g,o), hidden tx*4+i
        if (step < L - 1) {
#pragma unroll
            for (int i = 0; i < 4; ++i) {
                float cn0 = sigf(acc0[4 + i]) * creg[i] + sigf(acc0[i]) * tanhf(acc0[8 + i]);
                float hn0 = sigf(acc0[12 + i]) * tanhf(cn0);
                creg[i] = cn0;
                float cn1 = sigf(acc1[4 + i]) * creg[4 + i] + sigf(acc1[i]) * tanhf(acc1[8 + i]);
                float hn1 = sigf(acc1[12 + i]) * tanhf(cn1);
                creg[4 + i] = cn1;
                int hh = tx * 4 + i;
                A[(128 + hh) * ASTRIDE + 2 * ty] = hn0;
                A[(128 + hh) * ASTRIDE + 2 * ty + 1] = hn1;
            }
        } else {
            int n0 = (pga0 < P) ? paths[(size_t)pga0 * L + (L - 1)] : -1;
            int n1 = (pga1 < P) ? paths[(size_t)pga1 * L + (L - 1)] : -1;
#pragma unroll
            for (int i = 0; i < 4; ++i) {
                float cn0 = sigf(acc0[4 + i]) * creg[i] + sigf(acc0[i]) * tanhf(acc0[8 + i]);
                float hn0 = sigf(acc0[12 + i]) * tanhf(cn0);
                creg[i] = cn0;
                float cn1 = sigf(acc1[4 + i]) * creg[4 + i] + sigf(acc1[i]) * tanhf(acc1[8 + i]);
                float hn1 = sigf(acc1[12 + i]) * tanhf(cn1);
                creg[4 + i] = cn1;
                int hh = tx * 4 + i;
                if (n0 >= 0) atomicAdd(hsum + (size_t)n0 * HD + hh, hn0);
                if (n1 >= 0) atomicAdd(hsum + (size_t)n1 * HD + hh, hn1);
            }
        }
        // next step's gather writes rows 0..127 (disjoint from activation's
        // 128..191 and from last kb's reads 160..191); kb=0 barrier fences all.
    }
}

// ---------------------------------------------------------------------------
// Per-column sum / sumsq over rows (for BN stats)
// ---------------------------------------------------------------------------
__global__ void col_stats(const float* __restrict__ X, int nrows, float* __restrict__ out) {
    int col = threadIdx.x & 63, rg = threadIdx.x >> 6;
    float s = 0.f, q = 0.f;
    long stride = (long)gridDim.x * 4;
    for (long r = (long)blockIdx.x * 4 + rg; r < nrows; r += stride) {
        float v = X[r * 64 + col];
        s += v;
        q += v * v;
    }
    __shared__ float red[2][256];
    red[0][threadIdx.x] = s;
    red[1][threadIdx.x] = q;
    __syncthreads();
    if (threadIdx.x < 64) {
        int c = threadIdx.x;
        float ss = red[0][c] + red[0][c + 64] + red[0][c + 128] + red[0][c + 192];
        float qq = red[1][c] + red[1][c + 64] + red[1][c + 128] + red[1][c + 192];
        atomicAdd(out + c, ss);
        atomicAdd(out + 64 + c, qq);
    }
}

// stats -> per-column affine: y = x*a + c  implements BN(g,b)
__global__ void bn_finalize(const float* __restrict__ stats, const float* __restrict__ g,
                            const float* __restrict__ b, int nrows, float* __restrict__ ab) {
    int h = threadIdx.x;
    if (h >= 64) return;
    float inv = 1.0f / (float)nrows;
    float mean = stats[h] * inv;
    float var = stats[64 + h] * inv - mean * mean;
    float a = g[h] * rsqrtf(var + 1e-5f);
    ab[h] = a;
    ab[64 + h] = b[h] - mean * a;
}

// ---------------------------------------------------------------------------
// Y[n][j] = sum_k inAct(X[n][k]*a[k]+c[k]) * W[k][j] + bias[j]
// optional fused column stats of Y (pre-activation values of the NEXT BN)
// ---------------------------------------------------------------------------
template <bool INRELU, bool STATS>
__global__ __launch_bounds__(256)
void gemm64(const float* __restrict__ X, const float* __restrict__ ab,
            const float* __restrict__ W, const float* __restrict__ bias,
            float* __restrict__ Y, float* stats, int nrows) {
    __shared__ float Xs[64 * 64];
    __shared__ float red[2][256];
    const int t = threadIdx.x;
    const int col = t & 63, rg = t >> 6;
    const long r0 = (long)blockIdx.x * 64;

    float a = 1.f, c = 0.f;
    if (ab) { a = ab[col]; c = ab[64 + col]; }

    for (int i = 0; i < 16; ++i) {
        int rl = rg * 16 + i;
        long r = r0 + rl;
        float v = (r < nrows) ? X[r * 64 + col] : 0.f;
        v = v * a + c;
        if (INRELU) v = fmaxf(v, 0.f);
        Xs[rl * 64 + col] = v;
    }
    __syncthreads();

    float wreg[64];
#pragma unroll
    for (int k = 0; k < 64; ++k) wreg[k] = W[k * 64 + col];
    float bs = bias[col];
    float ssum = 0.f, ssq = 0.f;

    for (int i = 0; i < 16; ++i) {
        int rl = rg * 16 + i;
        long r = r0 + rl;
        const float4* xs4 = (const float4*)(Xs + rl * 64);
        float acc = bs;
#pragma unroll
        for (int k4 = 0; k4 < 16; ++k4) {
            float4 xv = xs4[k4];
            acc += xv.x * wreg[4 * k4] + xv.y * wreg[4 * k4 + 1] +
                   xv.z * wreg[4 * k4 + 2] + xv.w * wreg[4 * k4 + 3];
        }
        if (r < nrows) {
            Y[r * 64 + col] = acc;
            ssum += acc;
            ssq += acc * acc;
        }
    }
    if (STATS) {
        red[0][t] = ssum;
        red[1][t] = ssq;
        __syncthreads();
        if (t < 64) {
            float s = red[0][t] + red[0][t + 64] + red[0][t + 128] + red[0][t + 192];
            float q = red[1][t] + red[1][t + 64] + red[1][t + 128] + red[1][t + 192];
            atomicAdd(stats + t, s);
            atomicAdd(stats + 64 + t, q);
        }
    }
}

// Wio = relu(Wio*a + c); optionally Win = 0.75*W0 - 0.25*Wio
__global__ void bn_apply(float* __restrict__ Wio, const float* __restrict__ ab,
                         const float* __restrict__ W0, float* __restrict__ Win, long n) {
    long gid = (long)blockIdx.x * 256 + threadIdx.x;
    if (gid >= n * 64) return;
    int col = (int)(gid & 63);
    float v = fmaxf(Wio[gid] * ab[col] + ab[64 + col], 0.f);
    Wio[gid] = v;
    if (Win) Win[gid] = 0.75f * W0[gid] - 0.25f * v;
}

// per-column dots: atts[h] += sum_n W0*W1 ; atts[64+h] += sum_n W0*W2
__global__ void att_scores(const float* __restrict__ W0, const float* __restrict__ W1,
                           const float* __restrict__ W2, float* __restrict__ atts, int n) {
    int col = threadIdx.x & 63, rg = threadIdx.x >> 6;
    float s1 = 0.f, s2 = 0.f;
    long stride = (long)gridDim.x * 4;
    for (long r = (long)blockIdx.x * 4 + rg; r < n; r += stride) {
        float q = W0[r * 64 + col];
        s1 += q * W1[r * 64 + col];
        s2 += q * W2[r * 64 + col];
    }
    __shared__ float red[2][256];
    red[0][threadIdx.x] = s1;
    red[1][threadIdx.x] = s2;
    __syncthreads();
    if (threadIdx.x < 64) {
        int c = threadIdx.x;
        float a1 = red[0][c] + red[0][c + 64] + red[0][c + 128] + red[0][c + 192];
        float a2 = red[1][c] + red[1][c + 64] + red[1][c + 128] + red[1][c + 192];
        atomicAdd(atts + c, a1);
        atomicAdd(atts + 64 + c, a2);
    }
}

// single wave: normalize scores, dot w_att, softmax over the 2 -> watt[0..1]
__global__ void att_softmax(const float* __restrict__ atts, const float* __restrict__ w_att,
                            const float* __restrict__ b_att, float* __restrict__ watt) {
    int h = threadIdx.x;  // 0..63
    float z[2];
    for (int k = 0; k < 2; ++k) {
        float s = atts[64 * k + h];
        float mn = s, mx = s;
        for (int off = 32; off > 0; off >>= 1) {
            mn = fminf(mn, __shfl_down(mn, off));
            mx = fmaxf(mx, __shfl_down(mx, off));
        }
        mn = __shfl(mn, 0);
        mx = __shfl(mx, 0);
        float sn = (s - mn) / (mx - mn + 1e-6f);
        float d = sn * w_att[h];
        for (int off = 32; off > 0; off >>= 1) d += __shfl_down(d, off);
        z[k] = __shfl(d, 0) + b_att[0];
    }
    if (h == 0) {
        float m = fmaxf(z[0], z[1]);
        float e0 = expf(z[0] - m), e1 = expf(z[1] - m);
        float inv = 1.0f / (e0 + e1);
        watt[0] = e0 * inv;
        watt[1] = e1 * inv;
    }
}

// rep = W0 + w1*W1 + w2*W2, scatter-add into pooled[batch[n]]
__global__ void pool_rep(const float* __restrict__ W0, const float* __restrict__ W1,
                         const float* __restrict__ W2, const float* __restrict__ watt,
                         const int* __restrict__ batch, float* __restrict__ pooled, int n) {
    long gid = (long)blockIdx.x * 256 + threadIdx.x;
    if (gid >= (long)n * 64) return;
    long r = gid >> 6;
    int col = (int)(gid & 63);
    float w1 = watt[0], w2 = watt[1];
    float rep = W0[gid] + w1 * W1[gid] + w2 * W2[gid];
    atomicAdd(pooled + (size_t)batch[r] * 64 + col, rep);
}

// out[g][j] = sum_k relu(X[g][k]) * W[k][j] + b[j]   (W is 64 x 10)
__global__ void lin2_kernel(const float* __restrict__ X, const float* __restrict__ W,
                            const float* __restrict__ b, float* __restrict__ out, int g_count) {
    int gid = blockIdx.x * 256 + threadIdx.x;
    if (gid >= g_count * NCLS) return;
    int g = gid / NCLS, j = gid - g * NCLS;
    float acc = b[j];
    const float* xr = X + (size_t)g * 64;
    for (int k = 0; k < 64; ++k) acc += fmaxf(xr[k], 0.f) * W[k * NCLS + j];
    out[gid] = acc;
}

// ---------------------------------------------------------------------------
extern "C" void kernel_launch(void* const* d_in, const int* in_sizes, int n_in,
                              void* d_out, int out_size, void* d_ws, size_t ws_size,
                              hipStream_t stream) {
    const float* x         = (const float*)d_in[0];
    const float* edge_attr = (const float*)d_in[1];
    const int*   paths2    = (const int*)d_in[2];
    const int*   ei2       = (const int*)d_in[3];
    const int*   paths3    = (const int*)d_in[4];
    const int*   ei3       = (const int*)d_in[5];
    const int*   batch     = (const int*)d_in[6];
    const float* w_feat    = (const float*)d_in[7];
    const float* b_feat    = (const float*)d_in[8];
    const float* w_bond    = (const float*)d_in[9];
    const float* b_bond    = (const float*)d_in[10];
    const float* w_ih      = (const float*)d_in[11];
    const float* w_hh      = (const float*)d_in[12];
    const float* b_ih      = (const float*)d_in[13];
    const float* b_hh      = (const float*)d_in[14];
    const float* bn_g      = (const float*)d_in[15];
    const float* bn_b      = (const float*)d_in[16];
    const float* mlp_w1    = (const float*)d_in[17];
    const float* mlp_b1    = (const float*)d_in[18];
    const float* bn1_g     = (const float*)d_in[19];
    const float* bn1_b     = (const float*)d_in[20];
    const float* mlp_w2    = (const float*)d_in[21];
    const float* mlp_b2    = (const float*)d_in[22];
    const float* bn2_g     = (const float*)d_in[23];
    const float* bn2_b     = (const float*)d_in[24];
    const float* w_att     = (const float*)d_in[25];
    const float* b_att     = (const float*)d_in[26];
    const float* w_l1      = (const float*)d_in[27];
    const float* b_l1      = (const float*)d_in[28];
    const float* w_l2      = (const float*)d_in[29];
    const float* b_l2      = (const float*)d_in[30];

    float* ws = (float*)d_ws;
    float* W0     = ws;                               // N*64
    float* ea     = W0 + (size_t)NNODES * 64;         // E*64
    float* Win    = ea + (size_t)NEDGES * 64;         // N*64
    float* W1     = Win + (size_t)NNODES * 64;        // N*64
    float* W2     = W1 + (size_t)NNODES * 64;         // N*64
    float* Wtmp   = W2 + (size_t)NNODES * 64;         // N*64
    float* hsum   = Wtmp + (size_t)NNODES * 64;       // N*64
    float* Bt     = hsum + (size_t)NNODES * 64;       // 192*256
    float* bsum   = Bt + 192 * 256;                   // 256
    float* st     = bsum + 256;                       // 6*128
    float* abuf   = st + 6 * 128;                     // 6*128
    float* atts   = abuf + 6 * 128;                   // 128
    float* watt   = atts + 128;                       // 64 (2 used)
    float* pooled = watt + 64;                        // G*64
    float* lin1   = pooled + (size_t)NG * 64;         // G*64

    // zero: stats region (st..watt inclusive), pooled, hsum
    hipMemsetAsync(st, 0, (6 * 128 + 6 * 128 + 128 + 64) * sizeof(float), stream);
    hipMemsetAsync(pooled, 0, (size_t)NG * 64 * sizeof(float), stream);
    hipMemsetAsync(hsum, 0, (size_t)NNODES * 64 * sizeof(float), stream);

    prep_weights<<<193, 256, 0, stream>>>(w_ih, w_hh, b_ih, b_hh, Bt, bsum);
    encode<<<(NNODES * 64 + 255) / 256, 256, 0, stream>>>(x, w_feat, b_feat, W0, NNODES, NFEAT);
    encode<<<(NEDGES * 64 + 255) / 256, 256, 0, stream>>>(edge_attr, w_bond, b_bond, ea, NEDGES, EFEAT);

    // ---------------- conv 1 (L=2) ----------------
    conv_lstm<2><<<(NP2 + 31) / 32, 256, 0, stream>>>(W0, ea, paths2, ei2, Bt, bsum, hsum, NP2);

    col_stats<<<256, 256, 0, stream>>>(hsum, NNODES, st + 0);
    bn_finalize<<<1, 64, 0, stream>>>(st + 0, bn_g + 0, bn_b + 0, NNODES, abuf + 0);
    gemm64<false, true><<<(NNODES + 63) / 64, 256, 0, stream>>>(hsum, abuf + 0, mlp_w1, mlp_b1, Wtmp, st + 128, NNODES);
    bn_finalize<<<1, 64, 0, stream>>>(st + 128, bn1_g + 0, bn1_b + 0, NNODES, abuf + 128);
    gemm64<true, true><<<(NNODES + 63) / 64, 256, 0, stream>>>(Wtmp, abuf + 128, mlp_w2, mlp_b2, W1, st + 256, NNODES);
    bn_finalize<<<1, 64, 0, stream>>>(st + 256, bn2_g + 0, bn2_b + 0, NNODES, abuf + 256);
    bn_apply<<<(NNODES * 64 + 255) / 256, 256, 0, stream>>>(W1, abuf + 256, W0, Win, NNODES);

    // ---------------- conv 2 (L=3) ----------------
    hipMemsetAsync(hsum, 0, (size_t)NNODES * 64 * sizeof(float), stream);
    conv_lstm<3><<<(NP3 + 31) / 32, 256, 0, stream>>>(Win, ea, paths3, ei3, Bt, bsum, hsum, NP3);

    col_stats<<<256, 256, 0, stream>>>(hsum, NNODES, st + 384);
    bn_finalize<<<1, 64, 0, stream>>>(st + 384, bn_g + 64, bn_b + 64, NNODES, abuf + 384);
    gemm64<false, true><<<(NNODES + 63) / 64, 256, 0, stream>>>(hsum, abuf + 384, mlp_w1 + 4096, mlp_b1 + 64, Wtmp, st + 512, NNODES);
    bn_finalize<<<1, 64, 0, stream>>>(st + 512, bn1_g + 64, bn1_b + 64, NNODES, abuf + 512);
    gemm64<true, true><<<(NNODES + 63) / 64, 256, 0, stream>>>(Wtmp, abuf + 512, mlp_w2 + 4096, mlp_b2 + 64, W2, st + 640, NNODES);
    bn_finalize<<<1, 64, 0, stream>>>(st + 640, bn2_g + 64, bn2_b + 64, NNODES, abuf + 640);
    bn_apply<<<(NNODES * 64 + 255) / 256, 256, 0, stream>>>(W2, abuf + 640, nullptr, nullptr, NNODES);

    // ---------------- attention + pooling + head ----------------
    att_scores<<<256, 256, 0, stream>>>(W0, W1, W2, atts, NNODES);
    att_softmax<<<1, 64, 0, stream>>>(atts, w_att, b_att, watt);
    pool_rep<<<(NNODES * 64 + 255) / 256, 256, 0, stream>>>(W0, W1, W2, watt, batch, pooled, NNODES);
    gemm64<false, false><<<NG / 64, 256, 0, stream>>>(pooled, nullptr, w_l1, b_l1, lin1, nullptr, NG);
    lin2_kernel<<<(NG * NCLS + 255) / 256, 256, 0, stream>>>(lin1, w_l2, b_l2, (float*)d_out, NG);
}

// Round 3
// 1207.501 us; speedup vs baseline: 5.9638x; 4.3172x over previous
//
#include <hip/hip_runtime.h>
#include <math.h>

#define NNODES 100000
#define NEDGES 200000
#define HD 64
#define NP2 250000
#define NP3 500000
#define NG 2048
#define NCLS 10
#define NFEAT 18
#define EFEAT 18

typedef short short8v __attribute__((ext_vector_type(8)));
typedef float f32x4 __attribute__((ext_vector_type(4)));

__device__ __forceinline__ float fsig(float x) { return 1.0f / (1.0f + __expf(-x)); }
__device__ __forceinline__ float ftanh(float x) {
    float t = __expf(-2.0f * fabsf(x));
    float r = (1.0f - t) / (1.0f + t);
    return x < 0.f ? -r : r;
}

// pack two f32 -> bf16 pair (RNE), a in low 16, b in high 16
__device__ __forceinline__ unsigned bfpack(float a, float b) {
    unsigned ua = __builtin_bit_cast(unsigned, a);
    unsigned ub = __builtin_bit_cast(unsigned, b);
    ua = (ua + 0x7FFFu + ((ua >> 16) & 1u)) >> 16;
    ub = (ub + 0x7FFFu + ((ub >> 16) & 1u)) & 0xFFFF0000u;
    return ua | ub;
}
__device__ __forceinline__ unsigned short bf16r(float a) {
    unsigned u = __builtin_bit_cast(unsigned, a);
    return (unsigned short)((u + 0x7FFFu + ((u >> 16) & 1u)) >> 16);
}

// ---------------------------------------------------------------------------
// bsum[j] = b_ih[j] + b_hh[j]
// ---------------------------------------------------------------------------
__global__ void prep_bias(const float* __restrict__ b_ih, const float* __restrict__ b_hh,
                          float* __restrict__ bsum) {
    int j = threadIdx.x;
    bsum[j] = b_ih[j] + b_hh[j];
}

// ---------------------------------------------------------------------------
// Bp: bf16 B image, 6 chunks x [256 n x 40 shorts] (32 data + 8 pad).
// B[k][n] = k<128 ? w_ih[n][k] : w_hh[n][k-128];  stored transposed [n][k].
// ---------------------------------------------------------------------------
__global__ void prep_bp(const float* __restrict__ w_ih, const float* __restrict__ w_hh,
                        unsigned short* __restrict__ Bp) {
    int gid = blockIdx.x * 256 + threadIdx.x;
    if (gid >= 6 * 256 * 40) return;
    int c = gid / (256 * 40);
    int rem = gid - c * (256 * 40);
    int n = rem / 40, kk = rem - n * 40;
    unsigned short v = 0;
    if (kk < 32) {
        int k = c * 32 + kk;
        float f = (k < 128) ? w_ih[n * 128 + k] : w_hh[n * 64 + (k - 128)];
        v = bf16r(f);
    }
    Bp[gid] = v;
}

// ---------------------------------------------------------------------------
// Feature encoder: out[n][j] = sum_k X[n][k]*Wf[k][j] + bf[j]
// ---------------------------------------------------------------------------
__global__ void encode(const float* __restrict__ X, const float* __restrict__ Wf,
                       const float* __restrict__ bf, float* __restrict__ out,
                       long n, int F) {
    long gid = (long)blockIdx.x * 256 + threadIdx.x;
    if (gid >= n * 64) return;
    long r = gid >> 6;
    int col = (int)(gid & 63);
    float acc = bf[col];
    const float* xr = X + r * F;
    for (int k = 0; k < F; ++k) acc += xr[k] * Wf[k * 64 + col];
    out[gid] = acc;
}

// ---------------------------------------------------------------------------
// MFMA LSTM path conv. Block = 256 threads (4 waves) handles 64 paths.
// Al (LDS, bf16): [p=64][k], row stride 200 shorts; k 0..63 node feat,
// 64..127 edge enc, 128..191 h state.
// Bg (LDS, bf16): streamed B chunk [n=256][kk=32], row stride 40 shorts.
// Wave w computes m-tile w (16 paths) x all 16 n-tiles via
// mfma_f32_16x16x32_bf16; C layout: col=lane&15, row=(lane>>4)*4+reg.
// Lane (c=lane&15, q=lane>>4) owns paths {w*16+q*4+r} x hidden {c+16j}:
// i=acc[j][r], f=acc[4+j][r], g=acc[8+j][r], o=acc[12+j][r] -> activation
// fully in registers; h -> Al rows 128..191; final step scatters to hsum.
// Step 0 skips chunks 2..5 (edge=0, h=0) so no zero-init is needed.
// ---------------------------------------------------------------------------
template <int L>
__global__ __launch_bounds__(256, 3)
void conv_mfma(const float* __restrict__ x_in, const float* __restrict__ ea_enc,
               const int* __restrict__ paths, const int* __restrict__ ei,
               const unsigned short* __restrict__ Bp, const float* __restrict__ bsum,
               float* __restrict__ hsum, int P) {
    __shared__ unsigned short Al[64 * 200];
    __shared__ unsigned short Bg[256 * 40];

    const int t = threadIdx.x;
    const int w = t >> 6, lane = t & 63;
    const int c = lane & 15, q = lane >> 4;
    const int pl = t >> 2, gq = t & 3;          // gather: path-local, feat quarter
    const long pg = (long)blockIdx.x * 64 + pl;
    const int pc = (pg < P) ? (int)pg : P - 1;

    float breg[16];
#pragma unroll
    for (int j = 0; j < 16; ++j) breg[j] = bsum[j * 16 + c];
    float creg[16];
#pragma unroll
    for (int i = 0; i < 16; ++i) creg[i] = 0.f;

    f32x4 acc[16];

    for (int step = 0; step < L; ++step) {
        // ---- gather xt (and edge) -> Al rows, bf16
        {
            int node = paths[pc * L + step];
            const float4* s4 = (const float4*)(x_in + (size_t)node * HD + gq * 16);
            float4 f0 = s4[0], f1 = s4[1], f2 = s4[2], f3 = s4[3];
            uint4 u0, u1;
            u0.x = bfpack(f0.x, f0.y); u0.y = bfpack(f0.z, f0.w);
            u0.z = bfpack(f1.x, f1.y); u0.w = bfpack(f1.z, f1.w);
            u1.x = bfpack(f2.x, f2.y); u1.y = bfpack(f2.z, f2.w);
            u1.z = bfpack(f3.x, f3.y); u1.w = bfpack(f3.z, f3.w);
            *(uint4*)&Al[pl * 200 + gq * 16] = u0;
            *(uint4*)&Al[pl * 200 + gq * 16 + 8] = u1;
            if (step > 0) {
                int e = ei[pc * (L - 1) + (step - 1)];
                const float4* e4 = (const float4*)(ea_enc + (size_t)e * HD + gq * 16);
                float4 g0 = e4[0], g1 = e4[1], g2 = e4[2], g3 = e4[3];
                uint4 v0, v1;
                v0.x = bfpack(g0.x, g0.y); v0.y = bfpack(g0.z, g0.w);
                v0.z = bfpack(g1.x, g1.y); v0.w = bfpack(g1.z, g1.w);
                v1.x = bfpack(g2.x, g2.y); v1.y = bfpack(g2.z, g2.w);
                v1.z = bfpack(g3.x, g3.y); v1.w = bfpack(g3.z, g3.w);
                *(uint4*)&Al[pl * 200 + 64 + gq * 16] = v0;
                *(uint4*)&Al[pl * 200 + 64 + gq * 16 + 8] = v1;
            }
        }
        // ---- init accumulators with bias
#pragma unroll
        for (int j = 0; j < 16; ++j) {
            f32x4 v; v[0] = breg[j]; v[1] = breg[j]; v[2] = breg[j]; v[3] = breg[j];
            acc[j] = v;
        }
        // ---- MFMA GEMM over K chunks (step 0: only x-part, chunks 0..1)
        const int kc_end = (step == 0) ? 2 : 6;
        for (int kc = 0; kc < kc_end; ++kc) {
            __syncthreads();   // gather/h writes visible; prev Bg readers done
            {
                const float4* src = (const float4*)(Bp + kc * 10240);
                float4* dst = (float4*)Bg;
#pragma unroll
                for (int j = 0; j < 5; ++j) dst[t + j * 256] = src[t + j * 256];
            }
            __syncthreads();
            short8v af = *(const short8v*)&Al[(w * 16 + c) * 200 + kc * 32 + q * 8];
#pragma unroll
            for (int nt = 0; nt < 16; ++nt) {
                short8v bf = *(const short8v*)&Bg[(nt * 16 + c) * 40 + q * 8];
                acc[nt] = __builtin_amdgcn_mfma_f32_16x16x32_bf16(af, bf, acc[nt], 0, 0, 0);
            }
        }
        __syncthreads();       // all frag reads done before h-writeback
        // ---- activation (registers); cell (r,j): paths w*16+q*4+r, hidden c+16j
        if (step < L - 1) {
#pragma unroll
            for (int r = 0; r < 4; ++r) {
                int p = w * 16 + q * 4 + r;
#pragma unroll
                for (int j = 0; j < 4; ++j) {
                    float gi = acc[j][r], gf = acc[4 + j][r];
                    float gg = acc[8 + j][r], go = acc[12 + j][r];
                    float cn = fsig(gf) * creg[j * 4 + r] + fsig(gi) * ftanh(gg);
                    creg[j * 4 + r] = cn;
                    float hn = fsig(go) * ftanh(cn);
                    Al[p * 200 + 128 + c + 16 * j] = bf16r(hn);
                }
            }
        } else {
#pragma unroll
            for (int r = 0; r < 4; ++r) {
                long pr = (long)blockIdx.x * 64 + w * 16 + q * 4 + r;
                int node = (pr < P) ? paths[pr * L + (L - 1)] : -1;
#pragma unroll
                for (int j = 0; j < 4; ++j) {
                    float gi = acc[j][r], gf = acc[4 + j][r];
                    float gg = acc[8 + j][r], go = acc[12 + j][r];
                    float cn = fsig(gf) * creg[j * 4 + r] + fsig(gi) * ftanh(gg);
                    creg[j * 4 + r] = cn;
                    float hn = fsig(go) * ftanh(cn);
                    if (node >= 0) atomicAdd(hsum + (size_t)node * HD + c + 16 * j, hn);
                }
            }
        }
    }
}

// ---------------------------------------------------------------------------
// Per-column sum / sumsq over rows (for BN stats)
// ---------------------------------------------------------------------------
__global__ void col_stats(const float* __restrict__ X, int nrows, float* __restrict__ out) {
    int col = threadIdx.x & 63, rg = threadIdx.x >> 6;
    float s = 0.f, q = 0.f;
    long stride = (long)gridDim.x * 4;
    for (long r = (long)blockIdx.x * 4 + rg; r < nrows; r += stride) {
        float v = X[r * 64 + col];
        s += v;
        q += v * v;
    }
    __shared__ float red[2][256];
    red[0][threadIdx.x] = s;
    red[1][threadIdx.x] = q;
    __syncthreads();
    if (threadIdx.x < 64) {
        int c = threadIdx.x;
        float ss = red[0][c] + red[0][c + 64] + red[0][c + 128] + red[0][c + 192];
        float qq = red[1][c] + red[1][c + 64] + red[1][c + 128] + red[1][c + 192];
        atomicAdd(out + c, ss);
        atomicAdd(out + 64 + c, qq);
    }
}

// stats -> per-column affine: y = x*a + c  implements BN(g,b)
__global__ void bn_finalize(const float* __restrict__ stats, const float* __restrict__ g,
                            const float* __restrict__ b, int nrows, float* __restrict__ ab) {
    int h = threadIdx.x;
    if (h >= 64) return;
    float inv = 1.0f / (float)nrows;
    float mean = stats[h] * inv;
    float var = stats[64 + h] * inv - mean * mean;
    float a = g[h] * rsqrtf(var + 1e-5f);
    ab[h] = a;
    ab[64 + h] = b[h] - mean * a;
}

// ---------------------------------------------------------------------------
// Y[n][j] = sum_k inAct(X[n][k]*a[k]+c[k]) * W[k][j] + bias[j]
// optional fused column stats of Y
// ---------------------------------------------------------------------------
template <bool INRELU, bool STATS>
__global__ __launch_bounds__(256)
void gemm64(const float* __restrict__ X, const float* __restrict__ ab,
            const float* __restrict__ W, const float* __restrict__ bias,
            float* __restrict__ Y, float* stats, int nrows) {
    __shared__ float Xs[64 * 64];
    __shared__ float red[2][256];
    const int t = threadIdx.x;
    const int col = t & 63, rg = t >> 6;
    const long r0 = (long)blockIdx.x * 64;

    float a = 1.f, c = 0.f;
    if (ab) { a = ab[col]; c = ab[64 + col]; }

    for (int i = 0; i < 16; ++i) {
        int rl = rg * 16 + i;
        long r = r0 + rl;
        float v = (r < nrows) ? X[r * 64 + col] : 0.f;
        v = v * a + c;
        if (INRELU) v = fmaxf(v, 0.f);
        Xs[rl * 64 + col] = v;
    }
    __syncthreads();

    float wreg[64];
#pragma unroll
    for (int k = 0; k < 64; ++k) wreg[k] = W[k * 64 + col];
    float bs = bias[col];
    float ssum = 0.f, ssq = 0.f;

    for (int i = 0; i < 16; ++i) {
        int rl = rg * 16 + i;
        long r = r0 + rl;
        const float4* xs4 = (const float4*)(Xs + rl * 64);
        float acc = bs;
#pragma unroll
        for (int k4 = 0; k4 < 16; ++k4) {
            float4 xv = xs4[k4];
            acc += xv.x * wreg[4 * k4] + xv.y * wreg[4 * k4 + 1] +
                   xv.z * wreg[4 * k4 + 2] + xv.w * wreg[4 * k4 + 3];
        }
        if (r < nrows) {
            Y[r * 64 + col] = acc;
            ssum += acc;
            ssq += acc * acc;
        }
    }
    if (STATS) {
        red[0][t] = ssum;
        red[1][t] = ssq;
        __syncthreads();
        if (t < 64) {
            float s = red[0][t] + red[0][t + 64] + red[0][t + 128] + red[0][t + 192];
            float qq = red[1][t] + red[1][t + 64] + red[1][t + 128] + red[1][t + 192];
            atomicAdd(stats + t, s);
            atomicAdd(stats + 64 + t, qq);
        }
    }
}

// Wio = relu(Wio*a + c); optionally Win = 0.75*W0 - 0.25*Wio
__global__ void bn_apply(float* __restrict__ Wio, const float* __restrict__ ab,
                         const float* __restrict__ W0, float* __restrict__ Win, long n) {
    long gid = (long)blockIdx.x * 256 + threadIdx.x;
    if (gid >= n * 64) return;
    int col = (int)(gid & 63);
    float v = fmaxf(Wio[gid] * ab[col] + ab[64 + col], 0.f);
    Wio[gid] = v;
    if (Win) Win[gid] = 0.75f * W0[gid] - 0.25f * v;
}

// per-column dots: atts[h] += sum_n W0*W1 ; atts[64+h] += sum_n W0*W2
__global__ void att_scores(const float* __restrict__ W0, const float* __restrict__ W1,
                           const float* __restrict__ W2, float* __restrict__ atts, int n) {
    int col = threadIdx.x & 63, rg = threadIdx.x >> 6;
    float s1 = 0.f, s2 = 0.f;
    long stride = (long)gridDim.x * 4;
    for (long r = (long)blockIdx.x * 4 + rg; r < n; r += stride) {
        float q = W0[r * 64 + col];
        s1 += q * W1[r * 64 + col];
        s2 += q * W2[r * 64 + col];
    }
    __shared__ float red[2][256];
    red[0][threadIdx.x] = s1;
    red[1][threadIdx.x] = s2;
    __syncthreads();
    if (threadIdx.x < 64) {
        int c = threadIdx.x;
        float a1 = red[0][c] + red[0][c + 64] + red[0][c + 128] + red[0][c + 192];
        float a2 = red[1][c] + red[1][c + 64] + red[1][c + 128] + red[1][c + 192];
        atomicAdd(atts + c, a1);
        atomicAdd(atts + 64 + c, a2);
    }
}

// single wave: normalize scores, dot w_att, softmax over the 2 -> watt[0..1]
__global__ void att_softmax(const float* __restrict__ atts, const float* __restrict__ w_att,
                            const float* __restrict__ b_att, float* __restrict__ watt) {
    int h = threadIdx.x;  // 0..63
    float z[2];
    for (int k = 0; k < 2; ++k) {
        float s = atts[64 * k + h];
        float mn = s, mx = s;
        for (int off = 32; off > 0; off >>= 1) {
            mn = fminf(mn, __shfl_down(mn, off));
            mx = fmaxf(mx, __shfl_down(mx, off));
        }
        mn = __shfl(mn, 0);
        mx = __shfl(mx, 0);
        float sn = (s - mn) / (mx - mn + 1e-6f);
        float d = sn * w_att[h];
        for (int off = 32; off > 0; off >>= 1) d += __shfl_down(d, off);
        z[k] = __shfl(d, 0) + b_att[0];
    }
    if (h == 0) {
        float m = fmaxf(z[0], z[1]);
        float e0 = expf(z[0] - m), e1 = expf(z[1] - m);
        float inv = 1.0f / (e0 + e1);
        watt[0] = e0 * inv;
        watt[1] = e1 * inv;
    }
}

// rep = W0 + w1*W1 + w2*W2, scatter-add into pooled[batch[n]]
__global__ void pool_rep(const float* __restrict__ W0, const float* __restrict__ W1,
                         const float* __restrict__ W2, const float* __restrict__ watt,
                         const int* __restrict__ batch, float* __restrict__ pooled, int n) {
    long gid = (long)blockIdx.x * 256 + threadIdx.x;
    if (gid >= (long)n * 64) return;
    long r = gid >> 6;
    int col = (int)(gid & 63);
    float w1 = watt[0], w2 = watt[1];
    float rep = W0[gid] + w1 * W1[gid] + w2 * W2[gid];
    atomicAdd(pooled + (size_t)batch[r] * 64 + col, rep);
}

// out[g][j] = sum_k relu(X[g][k]) * W[k][j] + b[j]   (W is 64 x 10)
__global__ void lin2_kernel(const float* __restrict__ X, const float* __restrict__ W,
                            const float* __restrict__ b, float* __restrict__ out, int g_count) {
    int gid = blockIdx.x * 256 + threadIdx.x;
    if (gid >= g_count * NCLS) return;
    int g = gid / NCLS, j = gid - g * NCLS;
    float acc = b[j];
    const float* xr = X + (size_t)g * 64;
    for (int k = 0; k < 64; ++k) acc += fmaxf(xr[k], 0.f) * W[k * NCLS + j];
    out[gid] = acc;
}

// ---------------------------------------------------------------------------
extern "C" void kernel_launch(void* const* d_in, const int* in_sizes, int n_in,
                              void* d_out, int out_size, void* d_ws, size_t ws_size,
                              hipStream_t stream) {
    const float* x         = (const float*)d_in[0];
    const float* edge_attr = (const float*)d_in[1];
    const int*   paths2    = (const int*)d_in[2];
    const int*   ei2       = (const int*)d_in[3];
    const int*   paths3    = (const int*)d_in[4];
    const int*   ei3       = (const int*)d_in[5];
    const int*   batch     = (const int*)d_in[6];
    const float* w_feat    = (const float*)d_in[7];
    const float* b_feat    = (const float*)d_in[8];
    const float* w_bond    = (const float*)d_in[9];
    const float* b_bond    = (const float*)d_in[10];
    const float* w_ih      = (const float*)d_in[11];
    const float* w_hh      = (const float*)d_in[12];
    const float* b_ih      = (const float*)d_in[13];
    const float* b_hh      = (const float*)d_in[14];
    const float* bn_g      = (const float*)d_in[15];
    const float* bn_b      = (const float*)d_in[16];
    const float* mlp_w1    = (const float*)d_in[17];
    const float* mlp_b1    = (const float*)d_in[18];
    const float* bn1_g     = (const float*)d_in[19];
    const float* bn1_b     = (const float*)d_in[20];
    const float* bn2_g     = (const float*)d_in[23];
    const float* bn2_b     = (const float*)d_in[24];
    const float* mlp_w2    = (const float*)d_in[21];
    const float* mlp_b2    = (const float*)d_in[22];
    const float* w_att     = (const float*)d_in[25];
    const float* b_att     = (const float*)d_in[26];
    const float* w_l1      = (const float*)d_in[27];
    const float* b_l1      = (const float*)d_in[28];
    const float* w_l2      = (const float*)d_in[29];
    const float* b_l2      = (const float*)d_in[30];

    float* ws = (float*)d_ws;
    float* W0     = ws;                               // N*64
    float* ea     = W0 + (size_t)NNODES * 64;         // E*64
    float* Win    = ea + (size_t)NEDGES * 64;         // N*64
    float* W1     = Win + (size_t)NNODES * 64;        // N*64
    float* W2     = W1 + (size_t)NNODES * 64;         // N*64
    float* Wtmp   = W2 + (size_t)NNODES * 64;         // N*64
    float* hsum   = Wtmp + (size_t)NNODES * 64;       // N*64
    float* BpF    = hsum + (size_t)NNODES * 64;       // 6*256*40 ushorts = 30720 floats
    unsigned short* Bp = (unsigned short*)BpF;
    float* bsum   = BpF + 30720;                      // 256
    float* st     = bsum + 256;                       // 6*128
    float* abuf   = st + 6 * 128;                     // 6*128
    float* atts   = abuf + 6 * 128;                   // 128
    float* watt   = atts + 128;                       // 64 (2 used)
    float* pooled = watt + 64;                        // G*64
    float* lin1   = pooled + (size_t)NG * 64;         // G*64

    // zero: stats region (st..watt inclusive), pooled, hsum
    hipMemsetAsync(st, 0, (6 * 128 + 6 * 128 + 128 + 64) * sizeof(float), stream);
    hipMemsetAsync(pooled, 0, (size_t)NG * 64 * sizeof(float), stream);
    hipMemsetAsync(hsum, 0, (size_t)NNODES * 64 * sizeof(float), stream);

    prep_bias<<<1, 256, 0, stream>>>(b_ih, b_hh, bsum);
    prep_bp<<<240, 256, 0, stream>>>(w_ih, w_hh, Bp);
    encode<<<(NNODES * 64 + 255) / 256, 256, 0, stream>>>(x, w_feat, b_feat, W0, NNODES, NFEAT);
    encode<<<(NEDGES * 64 + 255) / 256, 256, 0, stream>>>(edge_attr, w_bond, b_bond, ea, NEDGES, EFEAT);

    // ---------------- conv 1 (L=2) ----------------
    conv_mfma<2><<<(NP2 + 63) / 64, 256, 0, stream>>>(W0, ea, paths2, ei2, Bp, bsum, hsum, NP2);

    col_stats<<<256, 256, 0, stream>>>(hsum, NNODES, st + 0);
    bn_finalize<<<1, 64, 0, stream>>>(st + 0, bn_g + 0, bn_b + 0, NNODES, abuf + 0);
    gemm64<false, true><<<(NNODES + 63) / 64, 256, 0, stream>>>(hsum, abuf + 0, mlp_w1, mlp_b1, Wtmp, st + 128, NNODES);
    bn_finalize<<<1, 64, 0, stream>>>(st + 128, bn1_g + 0, bn1_b + 0, NNODES, abuf + 128);
    gemm64<true, true><<<(NNODES + 63) / 64, 256, 0, stream>>>(Wtmp, abuf + 128, mlp_w2, mlp_b2, W1, st + 256, NNODES);
    bn_finalize<<<1, 64, 0, stream>>>(st + 256, bn2_g + 0, bn2_b + 0, NNODES, abuf + 256);
    bn_apply<<<(NNODES * 64 + 255) / 256, 256, 0, stream>>>(W1, abuf + 256, W0, Win, NNODES);

    // ---------------- conv 2 (L=3) ----------------
    hipMemsetAsync(hsum, 0, (size_t)NNODES * 64 * sizeof(float), stream);
    conv_mfma<3><<<(NP3 + 63) / 64, 256, 0, stream>>>(Win, ea, paths3, ei3, Bp, bsum, hsum, NP3);

    col_stats<<<256, 256, 0, stream>>>(hsum, NNODES, st + 384);
    bn_finalize<<<1, 64, 0, stream>>>(st + 384, bn_g + 64, bn_b + 64, NNODES, abuf + 384);
    gemm64<false, true><<<(NNODES + 63) / 64, 256, 0, stream>>>(hsum, abuf + 384, mlp_w1 + 4096, mlp_b1 + 64, Wtmp, st + 512, NNODES);
    bn_finalize<<<1, 64, 0, stream>>>(st + 512, bn1_g + 64, bn1_b + 64, NNODES, abuf + 512);
    gemm64<true, true><<<(NNODES + 63) / 64, 256, 0, stream>>>(Wtmp, abuf + 512, mlp_w2 + 4096, mlp_b2 + 64, W2, st + 640, NNODES);
    bn_finalize<<<1, 64, 0, stream>>>(st + 640, bn2_g + 64, bn2_b + 64, NNODES, abuf + 640);
    bn_apply<<<(NNODES * 64 + 255) / 256, 256, 0, stream>>>(W2, abuf + 640, nullptr, nullptr, NNODES);

    // ---------------- attention + pooling + head ----------------
    att_scores<<<256, 256, 0, stream>>>(W0, W1, W2, atts, NNODES);
    att_softmax<<<1, 64, 0, stream>>>(atts, w_att, b_att, watt);
    pool_rep<<<(NNODES * 64 + 255) / 256, 256, 0, stream>>>(W0, W1, W2, watt, batch, pooled, NNODES);
    gemm64<false, false><<<NG / 64, 256, 0, stream>>>(pooled, nullptr, w_l1, b_l1, lin1, nullptr, NG);
    lin2_kernel<<<(NG * NCLS + 255) / 256, 256, 0, stream>>>(lin1, w_l2, b_l2, (float*)d_out, NG);
}